// Round 11
// baseline (132.012 us; speedup 1.0000x reference)
//
#include <hip/hip_runtime.h>
#include <math.h>

#define T_STEPS 3
#define N_NODES 100000
#define N_EDGES 1600000
#define N_E4    (N_EDGES / 4)
#define D 64

#define CS_BLOCKS 782       // ceil(100000/128) colsum blocks per t

// Bucket parameters: 512-node buckets
#define BKT_BITS 9
#define BKT_SIZE 512
#define NBKT 196            // ceil(100000/512)
#define NBKT_PAD 256
#define QSCALE 65536.0f     // 2^16
#define QINV   (1.0f / 65536.0f)

// Chunk parameters: 4096 edges per chunk, chunk == scatter block
#define SC_EPB 4096
#define SC_I4  1024
#define SC_CHUNKS 391       // ceil(1.6M / 4096)

// smatvec-in-K3: 512 threads, 4 lanes/row -> 128 rows/block
#define SMV_BLOCKS 782

// GRU-rows parameters
#define GR_PAD 68

// Fallback parameters
#define PACK_SCALE 1048576.0f
#define PACK_INV   (1.0f / 1048576.0f)

// ---------------------------------------------------------------------------
// FAST ws layout (float offsets) — atomic-free, no memsets:
//   [0,4800000)        recs[3][E] u32   overlaid: colsumP[3][782][64] in
//                      [0,150144) (dead before K3 writes recs)
//   [4800000,5100288)  segStart[3][391][256] u32  (global record index of
//                      bucket b's segment within chunk c; written by prep)
//   [5100288,5100480)  v[3][64]
//   [5100480,5400480)  s[3][N]
// rec format: (dst&511)<<17 | src   (src < 2^17)
// ---------------------------------------------------------------------------

// K1: fused prep — blocks [0,782): colsum partials of x_t;
// blocks [782,1173): per-chunk dst hist + in-block scan -> segStart row.
__global__ __launch_bounds__(256) void prep_kernel(const float* __restrict__ x,
                                                   const int* __restrict__ dst,
                                                   float* __restrict__ colsumP,
                                                   unsigned* __restrict__ segStart) {
    const int t = blockIdx.y;
    const int tid = threadIdx.x;
    __shared__ float red[16][64];
    __shared__ unsigned h[NBKT_PAD];
    __shared__ unsigned scn[NBKT_PAD];

    if (blockIdx.x < CS_BLOCKS) {
        const int q = tid & 15;
        const int g = tid >> 4;
        const float4* xt = (const float4*)(x + (size_t)t * N_NODES * D);
        const int base = blockIdx.x * 128;
        float sx = 0.f, sy = 0.f, sz = 0.f, sw = 0.f;
#pragma unroll
        for (int it = 0; it < 8; ++it) {
            const int r = base + g + 16 * it;
            if (r < N_NODES) {
                const float4 vv = xt[(size_t)r * 16 + q];
                sx += vv.x; sy += vv.y; sz += vv.z; sw += vv.w;
            }
        }
        red[g][q * 4 + 0] = sx;
        red[g][q * 4 + 1] = sy;
        red[g][q * 4 + 2] = sz;
        red[g][q * 4 + 3] = sw;
        __syncthreads();
        if (tid < 64) {
            float s = 0.f;
#pragma unroll
            for (int gg = 0; gg < 16; ++gg) s += red[gg][tid];
            colsumP[((size_t)t * CS_BLOCKS + blockIdx.x) * 64 + tid] = s;
        }
    } else {
        const int c = blockIdx.x - CS_BLOCKS;
        h[tid] = 0;
        __syncthreads();
        const int4* dp = (const int4*)(dst + (size_t)t * N_EDGES);
#pragma unroll
        for (int it = 0; it < 4; ++it) {
            const int i4 = c * SC_I4 + it * 256 + tid;
            if (i4 < N_E4) {
                const int4 d = dp[i4];
                atomicAdd(&h[d.x >> BKT_BITS], 1u);
                atomicAdd(&h[d.y >> BKT_BITS], 1u);
                atomicAdd(&h[d.z >> BKT_BITS], 1u);
                atomicAdd(&h[d.w >> BKT_BITS], 1u);
            }
        }
        __syncthreads();
        const unsigned cval = h[tid];
        unsigned v = cval;
        scn[tid] = v;
        __syncthreads();
        for (int off = 1; off < NBKT_PAD; off <<= 1) {
            const unsigned add = (tid >= off) ? scn[tid - off] : 0u;
            __syncthreads();
            v += add;
            scn[tid] = v;
            __syncthreads();
        }
        segStart[((size_t)t * SC_CHUNKS + c) * NBKT_PAD + tid] =
            (unsigned)(c * SC_EPB) + (v - cval);
    }
}

__device__ __forceinline__ float fast_sigmoid(float v) {
    return 1.f / (1.f + __expf(-v));
}
__device__ __forceinline__ float fast_tanh(float v) {
    return 1.f - 2.f / (__expf(2.f * v) + 1.f);
}

// K2: row-parallel GRU, 16 blocks x 256 (4 rows per block, 1 wave per row).
__global__ __launch_bounds__(256) void gru_rows_kernel(
    const float* __restrict__ colsumP, const float* __restrict__ iw,
    const float* __restrict__ Wz, const float* __restrict__ bz,
    const float* __restrict__ Wr, const float* __restrict__ br,
    const float* __restrict__ Wh, const float* __restrict__ bh,
    const float* __restrict__ Wp, const float* __restrict__ bp,
    const float* __restrict__ Wo,
    float* __restrict__ v_out, float* __restrict__ w_final) {
    const int tid = threadIdx.x;
    __shared__ float BzT[64 * GR_PAD];
    __shared__ float BrT[64 * GR_PAD];
    __shared__ float BhT[64 * GR_PAD];
    __shared__ float w_lds[4 * 64];
    __shared__ float mean_s[192];
    __shared__ float ctx_s[192];
    __shared__ float czrh_s[576];

#pragma unroll
    for (int it = 0; it < 16; ++it) {
        const int idx = it * 256 + tid;
        const int k = idx >> 6, j = idx & 63;
        BzT[j * GR_PAD + k] = Wz[(64 + k) * 64 + j];
        BrT[j * GR_PAD + k] = Wr[(64 + k) * 64 + j];
        BhT[j * GR_PAD + k] = Wh[(64 + k) * 64 + j];
    }
    if (tid < 192) {
        const int t = tid >> 6, j = tid & 63;
        float s = 0.f;
        for (int bx = 0; bx < CS_BLOCKS; ++bx)
            s += colsumP[((size_t)t * CS_BLOCKS + bx) * 64 + j];
        mean_s[tid] = s * (1.f / (float)N_NODES);
    }
    __syncthreads();
    if (tid < 192) {
        const int t = tid >> 6, j = tid & 63;
        float c = bp[j];
        for (int k = 0; k < 64; ++k)
            c = fmaf(mean_s[t * 64 + k], Wp[k * 64 + j], c);
        ctx_s[tid] = c;
    }
    __syncthreads();
    for (int co = (tid >> 6); co < 9; co += 4) {
        const int t = co / 3, m = co - 3 * t, j = tid & 63;
        const float* W = (m == 0) ? Wz : (m == 1) ? Wr : Wh;
        const float* bb = (m == 0) ? bz : (m == 1) ? br : bh;
        float c = bb[j];
        for (int k = 0; k < 64; ++k)
            c = fmaf(ctx_s[t * 64 + k], W[k * 64 + j], c);
        czrh_s[co * 64 + j] = c;
    }
    __syncthreads();

    const int wid = tid >> 6, lane = tid & 63;
    const int row = blockIdx.x * 4 + wid;
    float* wrow = &w_lds[wid * 64];
    float w = iw[row * 64 + lane];
    const float wo = Wo[lane];

    for (int t = 0; t < T_STEPS; ++t) {
        wrow[lane] = w;
        __syncthreads();
        float az = 0.f, ar = 0.f;
#pragma unroll
        for (int k0 = 0; k0 < 64; k0 += 4) {
            const float4 wv = *(const float4*)&wrow[k0];
            const float4 z4 = *(const float4*)&BzT[lane * GR_PAD + k0];
            const float4 r4 = *(const float4*)&BrT[lane * GR_PAD + k0];
            az = fmaf(wv.x, z4.x, az); az = fmaf(wv.y, z4.y, az);
            az = fmaf(wv.z, z4.z, az); az = fmaf(wv.w, z4.w, az);
            ar = fmaf(wv.x, r4.x, ar); ar = fmaf(wv.y, r4.y, ar);
            ar = fmaf(wv.z, r4.z, ar); ar = fmaf(wv.w, r4.w, ar);
        }
        const float z = fast_sigmoid(az + czrh_s[(t * 3 + 0) * 64 + lane]);
        const float r = fast_sigmoid(ar + czrh_s[(t * 3 + 1) * 64 + lane]);
        const float rw = r * w;
        __syncthreads();
        wrow[lane] = rw;
        __syncthreads();
        float ah = 0.f;
#pragma unroll
        for (int k0 = 0; k0 < 64; k0 += 4) {
            const float4 wv = *(const float4*)&wrow[k0];
            const float4 h4 = *(const float4*)&BhT[lane * GR_PAD + k0];
            ah = fmaf(wv.x, h4.x, ah); ah = fmaf(wv.y, h4.y, ah);
            ah = fmaf(wv.z, h4.z, ah); ah = fmaf(wv.w, h4.w, ah);
        }
        const float h = fast_tanh(ah + czrh_s[(t * 3 + 2) * 64 + lane]);
        w = z * w + (1.f - z) * h;
        float vp = w * wo;
        vp += __shfl_xor(vp, 1);
        vp += __shfl_xor(vp, 2);
        vp += __shfl_xor(vp, 4);
        vp += __shfl_xor(vp, 8);
        vp += __shfl_xor(vp, 16);
        vp += __shfl_xor(vp, 32);
        if (lane == 0) v_out[t * 64 + row] = vp;
        __syncthreads();
    }
    w_final[row * 64 + lane] = w;
}

// K3: fused scatter (blocks [0,391)) + smatvec (blocks [391,1173)).
// Scatter: lofs from segStart (1 coalesced read), rank in LDS,
// CONTIGUOUS int4 writeout at c*4096 — 2 barriers total.
__global__ __launch_bounds__(512) void scat_smv_kernel(
    const float* __restrict__ x, const float* __restrict__ v,
    const int* __restrict__ src, const int* __restrict__ dst,
    const unsigned* __restrict__ segStart,
    unsigned* __restrict__ recs, float* __restrict__ s) {
    const int t = blockIdx.y;
    const int tid = threadIdx.x;
    __shared__ __align__(16) unsigned char lds_raw[17408];

    if (blockIdx.x >= SC_CHUNKS) {
        // ---- smatvec: 128 rows per block, 4 lanes per row ----
        float* vs = (float*)lds_raw;
        if (tid < 64) vs[tid] = v[t * 64 + tid];
        __syncthreads();
        const int row = (blockIdx.x - SC_CHUNKS) * 128 + (tid >> 2);
        const int l4 = tid & 3;
        if (row < N_NODES) {
            const float4* xr = (const float4*)(x + ((size_t)t * N_NODES + row) * D);
            float acc = 0.f;
#pragma unroll
            for (int i = 0; i < 4; ++i) {
                const int c = i * 4 + l4;
                const float4 xv = xr[c];
                acc += xv.x * vs[c * 4 + 0] + xv.y * vs[c * 4 + 1] +
                       xv.z * vs[c * 4 + 2] + xv.w * vs[c * 4 + 3];
            }
            acc += __shfl_xor(acc, 1);
            acc += __shfl_xor(acc, 2);
            if (l4 == 0) s[(size_t)t * N_NODES + row] = acc;
        }
        return;
    }

    // ---- scatter chunk c ----
    const int c = blockIdx.x;
    unsigned* recL = (unsigned*)lds_raw;                 // 4096 u32 = 16KB
    unsigned* lofs = (unsigned*)(lds_raw + 16384);       // 256 u32

    if (tid < NBKT_PAD)
        lofs[tid] = segStart[((size_t)t * SC_CHUNKS + c) * NBKT_PAD + tid] -
                    (unsigned)(c * SC_EPB);

    const int4* sp = (const int4*)(src + (size_t)t * N_EDGES);
    const int4* dp = (const int4*)(dst + (size_t)t * N_EDGES);

    unsigned rec[8];
    int bkt[8];
#pragma unroll
    for (int k = 0; k < 8; ++k) bkt[k] = -1;

#pragma unroll
    for (int it = 0; it < 2; ++it) {
        const int i4 = c * SC_I4 + it * 512 + tid;
        if (i4 < N_E4) {
            const int4 sv = sp[i4];
            const int4 dv = dp[i4];
            const int ss[4] = {sv.x, sv.y, sv.z, sv.w};
            const int dd[4] = {dv.x, dv.y, dv.z, dv.w};
#pragma unroll
            for (int j = 0; j < 4; ++j) {
                rec[it * 4 + j] = ((unsigned)(dd[j] & (BKT_SIZE - 1)) << 17) |
                                  (unsigned)ss[j];
                bkt[it * 4 + j] = dd[j] >> BKT_BITS;
            }
        }
    }
    __syncthreads();   // lofs ready, edges loaded
#pragma unroll
    for (int k = 0; k < 8; ++k) {
        if (bkt[k] >= 0) {
            const unsigned pos = atomicAdd(&lofs[bkt[k]], 1u);
            recL[pos] = rec[k];
        }
    }
    __syncthreads();
    const int nrecI4 = min(SC_I4, N_E4 - c * SC_I4);
    int4* outp = (int4*)(recs + (size_t)t * N_EDGES + (size_t)c * SC_EPB);
    const int4* inL = (const int4*)recL;
    for (int i = tid; i < nrecI4; i += 512) outp[i] = inL[i];
}

// K4: per-bucket accumulate — walk 391 per-chunk segments via segStart,
// gather s[src] (L2), integer u64 LDS bins (deterministic), finalize.
__global__ __launch_bounds__(256) void accum_kernel(const unsigned* __restrict__ recs,
                                                    const unsigned* __restrict__ segStart,
                                                    const float* __restrict__ s,
                                                    const float* __restrict__ bo,
                                                    float* __restrict__ out) {
    const int b = blockIdx.x;
    const int t = blockIdx.y;
    const int tid = threadIdx.x;
    __shared__ unsigned long long bins[BKT_SIZE];
    bins[tid] = 0ULL;
    bins[tid + 256] = 0ULL;
    __syncthreads();
    const float* st = s + (size_t)t * N_NODES;
    const unsigned* seg = segStart + (size_t)t * SC_CHUNKS * NBKT_PAD;
    const unsigned* rb = recs + (size_t)t * N_EDGES;
    for (int c = tid; c < SC_CHUNKS; c += 256) {
        const unsigned s0 = seg[c * NBKT_PAD + b];
        const unsigned s1 = seg[c * NBKT_PAD + b + 1];   // b<=195 -> b+1 valid
        for (unsigned i = s0; i < s1; ++i) {
            const unsigned rec = rb[i];
            const unsigned dl = rec >> 17;
            const long long q = llrintf(st[rec & 0x1FFFFu] * QSCALE);
            atomicAdd(&bins[dl],
                      (unsigned long long)((1ULL << 41) + (unsigned long long)q));
        }
    }
    __syncthreads();
    const float bo0 = bo[0];
#pragma unroll
    for (int k = 0; k < 2; ++k) {
        const int i = tid + k * 256;
        const int node = b * BKT_SIZE + i;
        if (node < N_NODES) {
            const unsigned long long tot = bins[i];
            const unsigned long long deg = (tot + (1ULL << 40)) >> 41;
            const long long rem = (long long)(tot - (deg << 41));
            const float acc = (float)rem * QINV;
            out[(size_t)t * N_NODES + node] = bo0 + acc / fmaxf((float)deg, 1.f);
        }
    }
}

// ---------- fallback path: packed global atomics ----------

__global__ __launch_bounds__(256) void smatvec_kernel(const float* __restrict__ x,
                                                      const float* __restrict__ v,
                                                      float* __restrict__ s) {
    const int t = blockIdx.y;
    const int tid = threadIdx.x;
    const int l4 = tid & 3;
    const int rloc = tid >> 2;
    __shared__ float vs[64];
    if (tid < 64) vs[tid] = v[t * 64 + tid];
    __syncthreads();
    const int row = blockIdx.x * 64 + rloc;
    if (row < N_NODES) {
        const float4* xr = (const float4*)(x + ((size_t)t * N_NODES + row) * D);
        float acc = 0.f;
#pragma unroll
        for (int i = 0; i < 4; ++i) {
            const int c = i * 4 + l4;
            const float4 xv = xr[c];
            acc += xv.x * vs[c * 4 + 0] + xv.y * vs[c * 4 + 1] +
                   xv.z * vs[c * 4 + 2] + xv.w * vs[c * 4 + 3];
        }
        acc += __shfl_xor(acc, 1);
        acc += __shfl_xor(acc, 2);
        if (l4 == 0) s[(size_t)t * N_NODES + row] = acc;
    }
}

__global__ __launch_bounds__(256) void edge_kernel(const int* __restrict__ src,
                                                   const int* __restrict__ dst,
                                                   const float* __restrict__ s,
                                                   unsigned long long* __restrict__ packed) {
    const int t = blockIdx.y;
    const int e4 = blockIdx.x * 256 + threadIdx.x;
    if (e4 * 4 >= N_EDGES) return;
    const int4* sp = (const int4*)(src + (size_t)t * N_EDGES);
    const int4* dp = (const int4*)(dst + (size_t)t * N_EDGES);
    const float* st = s + (size_t)t * N_NODES;
    unsigned long long* pk = packed + (size_t)t * N_NODES;
    const int4 s4 = sp[e4];
    const int4 d4 = dp[e4];
    const float v0 = st[s4.x], v1 = st[s4.y], v2 = st[s4.z], v3 = st[s4.w];
    const unsigned long long base = 1ULL << 41;
    atomicAdd(&pk[d4.x], base + (unsigned long long)(long long)llrintf(v0 * PACK_SCALE));
    atomicAdd(&pk[d4.y], base + (unsigned long long)(long long)llrintf(v1 * PACK_SCALE));
    atomicAdd(&pk[d4.z], base + (unsigned long long)(long long)llrintf(v2 * PACK_SCALE));
    atomicAdd(&pk[d4.w], base + (unsigned long long)(long long)llrintf(v3 * PACK_SCALE));
}

__global__ __launch_bounds__(256) void out_kernel(const unsigned long long* __restrict__ packed,
                                                  const float* __restrict__ bo,
                                                  float* __restrict__ out) {
    const int i = blockIdx.x * 256 + threadIdx.x;
    if (i < T_STEPS * N_NODES) {
        const unsigned long long tot = packed[i];
        const unsigned long long deg = (tot + (1ULL << 40)) >> 41;
        const long long rem = (long long)(tot - (deg << 41));
        const float acc = (float)rem * PACK_INV;
        out[i] = bo[0] + acc / fmaxf((float)deg, 1.0f);
    }
}

extern "C" void kernel_launch(void* const* d_in, const int* in_sizes, int n_in,
                              void* d_out, int out_size, void* d_ws, size_t ws_size,
                              hipStream_t stream) {
    const float* x  = (const float*)d_in[0];
    const int* src  = (const int*)d_in[1];
    const int* dst  = (const int*)d_in[2];
    const float* iw = (const float*)d_in[3];
    const float* Wz = (const float*)d_in[4];
    const float* bz = (const float*)d_in[5];
    const float* Wr = (const float*)d_in[6];
    const float* br = (const float*)d_in[7];
    const float* Wh = (const float*)d_in[8];
    const float* bh = (const float*)d_in[9];
    const float* Wp = (const float*)d_in[10];
    const float* bp = (const float*)d_in[11];
    const float* Wo = (const float*)d_in[12];
    const float* bo = (const float*)d_in[13];
    float* out = (float*)d_out;   // [3*N outs][64*64 w_final]
    float* ws  = (float*)d_ws;

    const size_t FAST_NEED = (size_t)5400480 * sizeof(float);
    if (ws_size >= FAST_NEED) {
        unsigned* recs     = (unsigned*)ws;              // [0,4800000)
        float* colsumP     = ws;                         // [0,150144) dead before K3
        unsigned* segStart = (unsigned*)(ws + 4800000);  // 300288 u32
        float* vbuf        = ws + 5100288;               // 192
        float* sbuf        = ws + 5100480;               // 300000

        prep_kernel<<<dim3(CS_BLOCKS + SC_CHUNKS, 3), 256, 0, stream>>>(x, dst,
                                                                        colsumP, segStart);
        gru_rows_kernel<<<16, 256, 0, stream>>>(colsumP, iw, Wz, bz, Wr, br, Wh, bh,
                                                Wp, bp, Wo, vbuf,
                                                out + (size_t)T_STEPS * N_NODES);
        scat_smv_kernel<<<dim3(SC_CHUNKS + SMV_BLOCKS, 3), 512, 0, stream>>>(
            x, vbuf, src, dst, segStart, recs, sbuf);
        accum_kernel<<<dim3(NBKT, 3), 256, 0, stream>>>(recs, segStart, sbuf, bo, out);
    } else {
        float* colsumP = ws;                                        // 150144
        float* vbuf    = ws + 150144;                               // 192
        float* sbuf    = ws + 150336;                               // 300000
        unsigned long long* packed = (unsigned long long*)(ws + 450336); // 300000 u64

        hipMemsetAsync(packed, 0, (size_t)600000 * sizeof(float), stream);

        prep_kernel<<<dim3(CS_BLOCKS, 3), 256, 0, stream>>>(x, dst, colsumP,
                                                            (unsigned*)nullptr);
        gru_rows_kernel<<<16, 256, 0, stream>>>(colsumP, iw, Wz, bz, Wr, br, Wh, bh,
                                                Wp, bp, Wo, vbuf,
                                                out + (size_t)T_STEPS * N_NODES);
        smatvec_kernel<<<dim3(1563, 3), 256, 0, stream>>>(x, vbuf, sbuf);
        edge_kernel<<<dim3(1563, 3), 256, 0, stream>>>(src, dst, sbuf, packed);
        out_kernel<<<1172, 256, 0, stream>>>(packed, bo, out);
    }
}

// Round 12
// 110.140 us; speedup vs baseline: 1.1986x; 1.1986x over previous
//
#include <hip/hip_runtime.h>
#include <math.h>

#define T_STEPS 3
#define N_NODES 100000
#define N_EDGES 1600000
#define N_E4    (N_EDGES / 4)
#define D 64

#define CS_BLOCKS 782       // ceil(100000/128) colsum blocks per t

// Bucket parameters: 64 buckets of 2048 nodes
#define BKT_BITS 11
#define BKT_SIZE 2048
#define NBKT 49             // ceil(100000/2048)
#define NBKT_PAD 64
#define QSCALE 65536.0f     // 2^16
#define QINV   (1.0f / 65536.0f)

// Chunk parameters: 4096 edges per chunk, chunk == scatter block
#define SC_EPB 4096
#define SC_I4  1024
#define SC_CHUNKS 391       // ceil(1.6M / 4096)

// smatvec-in-K3: 512 threads, 4 lanes/row -> 128 rows/block
#define SMV_BLOCKS 782

// GRU-rows parameters
#define GR_PAD 68

// Fallback parameters
#define PACK_SCALE 1048576.0f
#define PACK_INV   (1.0f / 1048576.0f)

// ---------------------------------------------------------------------------
// FAST ws layout (float offsets) — atomic-free, no memsets:
//   [0,4800000)        recs[3][E] u32   overlaid (dead before K3):
//        [0,150144)        colsumP[3][782][64]
//        [150144,225216)   histChunk[3][391][64] u32
//   [4800000,4875072)  chunkPref[3][391][64] u32
//   [4875072,4875264)  bstart[3][64] u32
//   [4875264,4875456)  v[3][64]
//   [4875456,5175456)  s[3][N]
// rec format: (dst&2047)<<17 | src   (src < 2^17)
// recs layout: bucket-contiguous per t (scatter writes runs, accum reads
// coalesced — the sort pays on the write side only).
// ---------------------------------------------------------------------------

// K1: fused prep — blocks [0,782): colsum partials of x_t;
// blocks [782,1173): per-chunk dst bucket histograms (64 buckets).
__global__ __launch_bounds__(256) void prep_kernel(const float* __restrict__ x,
                                                   const int* __restrict__ dst,
                                                   float* __restrict__ colsumP,
                                                   unsigned* __restrict__ histChunk) {
    const int t = blockIdx.y;
    const int tid = threadIdx.x;
    __shared__ float red[16][64];
    __shared__ unsigned h[NBKT_PAD];

    if (blockIdx.x < CS_BLOCKS) {
        const int q = tid & 15;
        const int g = tid >> 4;
        const float4* xt = (const float4*)(x + (size_t)t * N_NODES * D);
        const int base = blockIdx.x * 128;
        float sx = 0.f, sy = 0.f, sz = 0.f, sw = 0.f;
#pragma unroll
        for (int it = 0; it < 8; ++it) {
            const int r = base + g + 16 * it;
            if (r < N_NODES) {
                const float4 vv = xt[(size_t)r * 16 + q];
                sx += vv.x; sy += vv.y; sz += vv.z; sw += vv.w;
            }
        }
        red[g][q * 4 + 0] = sx;
        red[g][q * 4 + 1] = sy;
        red[g][q * 4 + 2] = sz;
        red[g][q * 4 + 3] = sw;
        __syncthreads();
        if (tid < 64) {
            float s = 0.f;
#pragma unroll
            for (int gg = 0; gg < 16; ++gg) s += red[gg][tid];
            colsumP[((size_t)t * CS_BLOCKS + blockIdx.x) * 64 + tid] = s;
        }
    } else {
        const int c = blockIdx.x - CS_BLOCKS;
        if (tid < NBKT_PAD) h[tid] = 0;
        __syncthreads();
        const int4* dp = (const int4*)(dst + (size_t)t * N_EDGES);
#pragma unroll
        for (int it = 0; it < 4; ++it) {
            const int i4 = c * SC_I4 + it * 256 + tid;
            if (i4 < N_E4) {
                const int4 d = dp[i4];
                atomicAdd(&h[d.x >> BKT_BITS], 1u);
                atomicAdd(&h[d.y >> BKT_BITS], 1u);
                atomicAdd(&h[d.z >> BKT_BITS], 1u);
                atomicAdd(&h[d.w >> BKT_BITS], 1u);
            }
        }
        __syncthreads();
        if (tid < NBKT_PAD)
            histChunk[((size_t)t * SC_CHUNKS + c) * NBKT_PAD + tid] = h[tid];
    }
}

__device__ __forceinline__ float fast_sigmoid(float v) {
    return 1.f / (1.f + __expf(-v));
}
__device__ __forceinline__ float fast_tanh(float v) {
    return 1.f - 2.f / (__expf(2.f * v) + 1.f);
}

// K2: blocks 0..15 GRU rows; block 16 bucket-total scan -> bstart;
// blocks 17..64 per-(chunk,bucket) exclusive prefixes -> chunkPref.
__global__ __launch_bounds__(256) void gru_rows_kernel(
    const float* __restrict__ colsumP, const float* __restrict__ iw,
    const float* __restrict__ Wz, const float* __restrict__ bz,
    const float* __restrict__ Wr, const float* __restrict__ br,
    const float* __restrict__ Wh, const float* __restrict__ bh,
    const float* __restrict__ Wp, const float* __restrict__ bp,
    const float* __restrict__ Wo, const unsigned* __restrict__ histChunk,
    unsigned* __restrict__ bstart, unsigned* __restrict__ chunkPref,
    float* __restrict__ v_out, float* __restrict__ w_final) {
    const int tid = threadIdx.x;

    if (blockIdx.x == 16) {
        // bucket totals + single-wave exclusive scan -> bstart[t][b]
        if (tid < NBKT_PAD) {
            for (int t = 0; t < T_STEPS; ++t) {
                unsigned c = 0;
                for (int k = 0; k < SC_CHUNKS; ++k)
                    c += histChunk[((size_t)t * SC_CHUNKS + k) * NBKT_PAD + tid];
                unsigned v = c;
#pragma unroll
                for (int off = 1; off < 64; off <<= 1) {
                    const unsigned n = __shfl_up(v, off);
                    if (tid >= off) v += n;
                }
                bstart[t * NBKT_PAD + tid] = (unsigned)(t * N_EDGES) + (v - c);
            }
        }
        return;
    }
    if (blockIdx.x >= 17) {
        // chunk-prefix per bucket: one wave per (t,b)
        const int idx = blockIdx.x - 17;      // 0..47
        const int t = idx >> 4;               // 0..2
        const int wid = tid >> 6, lane = tid & 63;
        const int b = (idx & 15) * 4 + wid;   // 0..63
        unsigned running = 0;
#pragma unroll
        for (int g = 0; g < 7; ++g) {
            const int c = g * 64 + lane;
            const unsigned val = (c < SC_CHUNKS)
                ? histChunk[((size_t)t * SC_CHUNKS + c) * NBKT_PAD + b] : 0u;
            unsigned incl = val;
#pragma unroll
            for (int off = 1; off < 64; off <<= 1) {
                const unsigned n = __shfl_up(incl, off);
                if (lane >= off) incl += n;
            }
            if (c < SC_CHUNKS)
                chunkPref[((size_t)t * SC_CHUNKS + c) * NBKT_PAD + b] = running + (incl - val);
            running += __shfl(incl, 63);
        }
        return;
    }

    // ---- GRU rows block ----
    __shared__ float BzT[64 * GR_PAD];
    __shared__ float BrT[64 * GR_PAD];
    __shared__ float BhT[64 * GR_PAD];
    __shared__ float w_lds[4 * 64];
    __shared__ float mean_s[192];
    __shared__ float ctx_s[192];
    __shared__ float czrh_s[576];

#pragma unroll
    for (int it = 0; it < 16; ++it) {
        const int idx = it * 256 + tid;
        const int k = idx >> 6, j = idx & 63;
        BzT[j * GR_PAD + k] = Wz[(64 + k) * 64 + j];
        BrT[j * GR_PAD + k] = Wr[(64 + k) * 64 + j];
        BhT[j * GR_PAD + k] = Wh[(64 + k) * 64 + j];
    }
    if (tid < 192) {
        const int t = tid >> 6, j = tid & 63;
        float s = 0.f;
        for (int bx = 0; bx < CS_BLOCKS; ++bx)
            s += colsumP[((size_t)t * CS_BLOCKS + bx) * 64 + j];
        mean_s[tid] = s * (1.f / (float)N_NODES);
    }
    __syncthreads();
    if (tid < 192) {
        const int t = tid >> 6, j = tid & 63;
        float c = bp[j];
        for (int k = 0; k < 64; ++k)
            c = fmaf(mean_s[t * 64 + k], Wp[k * 64 + j], c);
        ctx_s[tid] = c;
    }
    __syncthreads();
    for (int co = (tid >> 6); co < 9; co += 4) {
        const int t = co / 3, m = co - 3 * t, j = tid & 63;
        const float* W = (m == 0) ? Wz : (m == 1) ? Wr : Wh;
        const float* bb = (m == 0) ? bz : (m == 1) ? br : bh;
        float c = bb[j];
        for (int k = 0; k < 64; ++k)
            c = fmaf(ctx_s[t * 64 + k], W[k * 64 + j], c);
        czrh_s[co * 64 + j] = c;
    }
    __syncthreads();

    const int wid = tid >> 6, lane = tid & 63;
    const int row = blockIdx.x * 4 + wid;
    float* wrow = &w_lds[wid * 64];
    float w = iw[row * 64 + lane];
    const float wo = Wo[lane];

    for (int t = 0; t < T_STEPS; ++t) {
        wrow[lane] = w;
        __syncthreads();
        float az = 0.f, ar = 0.f;
#pragma unroll
        for (int k0 = 0; k0 < 64; k0 += 4) {
            const float4 wv = *(const float4*)&wrow[k0];
            const float4 z4 = *(const float4*)&BzT[lane * GR_PAD + k0];
            const float4 r4 = *(const float4*)&BrT[lane * GR_PAD + k0];
            az = fmaf(wv.x, z4.x, az); az = fmaf(wv.y, z4.y, az);
            az = fmaf(wv.z, z4.z, az); az = fmaf(wv.w, z4.w, az);
            ar = fmaf(wv.x, r4.x, ar); ar = fmaf(wv.y, r4.y, ar);
            ar = fmaf(wv.z, r4.z, ar); ar = fmaf(wv.w, r4.w, ar);
        }
        const float z = fast_sigmoid(az + czrh_s[(t * 3 + 0) * 64 + lane]);
        const float r = fast_sigmoid(ar + czrh_s[(t * 3 + 1) * 64 + lane]);
        const float rw = r * w;
        __syncthreads();
        wrow[lane] = rw;
        __syncthreads();
        float ah = 0.f;
#pragma unroll
        for (int k0 = 0; k0 < 64; k0 += 4) {
            const float4 wv = *(const float4*)&wrow[k0];
            const float4 h4 = *(const float4*)&BhT[lane * GR_PAD + k0];
            ah = fmaf(wv.x, h4.x, ah); ah = fmaf(wv.y, h4.y, ah);
            ah = fmaf(wv.z, h4.z, ah); ah = fmaf(wv.w, h4.w, ah);
        }
        const float h = fast_tanh(ah + czrh_s[(t * 3 + 2) * 64 + lane]);
        w = z * w + (1.f - z) * h;
        float vp = w * wo;
        vp += __shfl_xor(vp, 1);
        vp += __shfl_xor(vp, 2);
        vp += __shfl_xor(vp, 4);
        vp += __shfl_xor(vp, 8);
        vp += __shfl_xor(vp, 16);
        vp += __shfl_xor(vp, 32);
        if (lane == 0) v_out[t * 64 + row] = vp;
        __syncthreads();
    }
    w_final[row * 64 + lane] = w;
}

// K3: fused scatter (blocks [0,391)) + smatvec (blocks [391,1173)).
// Scatter: hist -> 1-wave scan -> rank -> bucket-run writeout (~256B runs).
__global__ __launch_bounds__(512) void scat_smv_kernel(
    const float* __restrict__ x, const float* __restrict__ v,
    const int* __restrict__ src, const int* __restrict__ dst,
    const unsigned* __restrict__ bstart, const unsigned* __restrict__ chunkPref,
    unsigned* __restrict__ recs, float* __restrict__ s) {
    const int t = blockIdx.y;
    const int tid = threadIdx.x;
    __shared__ __align__(16) unsigned char lds_raw[21504];

    if (blockIdx.x >= SC_CHUNKS) {
        // ---- smatvec: 128 rows per block, 4 lanes per row ----
        float* vs = (float*)lds_raw;
        if (tid < 64) vs[tid] = v[t * 64 + tid];
        __syncthreads();
        const int row = (blockIdx.x - SC_CHUNKS) * 128 + (tid >> 2);
        const int l4 = tid & 3;
        if (row < N_NODES) {
            const float4* xr = (const float4*)(x + ((size_t)t * N_NODES + row) * D);
            float acc = 0.f;
#pragma unroll
            for (int i = 0; i < 4; ++i) {
                const int c = i * 4 + l4;
                const float4 xv = xr[c];
                acc += xv.x * vs[c * 4 + 0] + xv.y * vs[c * 4 + 1] +
                       xv.z * vs[c * 4 + 2] + xv.w * vs[c * 4 + 3];
            }
            acc += __shfl_xor(acc, 1);
            acc += __shfl_xor(acc, 2);
            if (l4 == 0) s[(size_t)t * N_NODES + row] = acc;
        }
        return;
    }

    // ---- scatter chunk c ----
    const int c = blockIdx.x;
    unsigned* recL = (unsigned*)lds_raw;                   // 4096 u32 = 16KB
    unsigned char* bktL = (unsigned char*)(lds_raw + 16384); // 4096 u8
    unsigned* bh   = (unsigned*)(lds_raw + 20480);         // 64
    unsigned* lofs = bh + 64;                              // 64
    unsigned* badj = lofs + 64;                            // 64

    if (tid < NBKT_PAD) bh[tid] = 0;
    __syncthreads();

    const int4* sp = (const int4*)(src + (size_t)t * N_EDGES);
    const int4* dp = (const int4*)(dst + (size_t)t * N_EDGES);

    unsigned rec[8];
    int bkt[8];
#pragma unroll
    for (int k = 0; k < 8; ++k) bkt[k] = -1;

#pragma unroll
    for (int it = 0; it < 2; ++it) {
        const int i4 = c * SC_I4 + it * 512 + tid;
        if (i4 < N_E4) {
            const int4 sv = sp[i4];
            const int4 dv = dp[i4];
            const int ss[4] = {sv.x, sv.y, sv.z, sv.w};
            const int dd[4] = {dv.x, dv.y, dv.z, dv.w};
#pragma unroll
            for (int j = 0; j < 4; ++j) {
                const int b = dd[j] >> BKT_BITS;
                rec[it * 4 + j] = ((unsigned)(dd[j] & (BKT_SIZE - 1)) << 17) |
                                  (unsigned)ss[j];
                bkt[it * 4 + j] = b;
                atomicAdd(&bh[b], 1u);
            }
        }
    }
    __syncthreads();
    // single-wave exclusive scan over 64 buckets + base computation
    if (tid < 64) {
        const unsigned cnt = bh[tid];
        unsigned v = cnt;
#pragma unroll
        for (int off = 1; off < 64; off <<= 1) {
            const unsigned n = __shfl_up(v, off);
            if (tid >= off) v += n;
        }
        const unsigned ex = v - cnt;
        lofs[tid] = ex;
        const unsigned base = bstart[t * NBKT_PAD + tid] +
                              chunkPref[((size_t)t * SC_CHUNKS + c) * NBKT_PAD + tid];
        badj[tid] = base - ex;   // mod 2^32 ok
    }
    __syncthreads();
#pragma unroll
    for (int k = 0; k < 8; ++k) {
        if (bkt[k] >= 0) {
            const unsigned pos = atomicAdd(&lofs[bkt[k]], 1u);
            recL[pos] = rec[k];
            bktL[pos] = (unsigned char)bkt[k];
        }
    }
    __syncthreads();
    const int nrec = min(SC_EPB, N_EDGES - c * SC_EPB);
    for (int i = tid; i < nrec; i += 512) {
        const unsigned b = bktL[i];
        recs[badj[b] + (unsigned)i] = recL[i];
    }
}

// K4: per-bucket accumulate — coalesced contiguous record reads,
// gather s[src] (L2), integer u64 LDS bins (deterministic), finalize.
__global__ __launch_bounds__(512) void accum_kernel(const unsigned* __restrict__ recs,
                                                    const unsigned* __restrict__ start,
                                                    const float* __restrict__ s,
                                                    const float* __restrict__ bo,
                                                    float* __restrict__ out) {
    const int b = blockIdx.x;
    const int t = blockIdx.y;
    const int tid = threadIdx.x;
    __shared__ unsigned long long bins[BKT_SIZE];
#pragma unroll
    for (int k = 0; k < 4; ++k) bins[tid + k * 512] = 0ULL;
    __syncthreads();
    const float* st = s + (size_t)t * N_NODES;
    const unsigned s0 = start[t * NBKT_PAD + b];
    const unsigned s1 = start[t * NBKT_PAD + b + 1];
    for (unsigned i = s0 + tid; i < s1; i += 512) {
        const unsigned rec = recs[i];
        const unsigned dl = rec >> 17;
        const long long q = llrintf(st[rec & 0x1FFFFu] * QSCALE);
        atomicAdd(&bins[dl],
                  (unsigned long long)((1ULL << 41) + (unsigned long long)q));
    }
    __syncthreads();
    const float bo0 = bo[0];
#pragma unroll
    for (int k = 0; k < 4; ++k) {
        const int i = tid + k * 512;
        const int node = b * BKT_SIZE + i;
        if (node < N_NODES) {
            const unsigned long long tot = bins[i];
            const unsigned long long deg = (tot + (1ULL << 40)) >> 41;
            const long long rem = (long long)(tot - (deg << 41));
            const float acc = (float)rem * QINV;
            out[(size_t)t * N_NODES + node] = bo0 + acc / fmaxf((float)deg, 1.f);
        }
    }
}

// ---------- fallback path: packed global atomics ----------

__global__ __launch_bounds__(256) void smatvec_kernel(const float* __restrict__ x,
                                                      const float* __restrict__ v,
                                                      float* __restrict__ s) {
    const int t = blockIdx.y;
    const int tid = threadIdx.x;
    const int l4 = tid & 3;
    const int rloc = tid >> 2;
    __shared__ float vs[64];
    if (tid < 64) vs[tid] = v[t * 64 + tid];
    __syncthreads();
    const int row = blockIdx.x * 64 + rloc;
    if (row < N_NODES) {
        const float4* xr = (const float4*)(x + ((size_t)t * N_NODES + row) * D);
        float acc = 0.f;
#pragma unroll
        for (int i = 0; i < 4; ++i) {
            const int c = i * 4 + l4;
            const float4 xv = xr[c];
            acc += xv.x * vs[c * 4 + 0] + xv.y * vs[c * 4 + 1] +
                   xv.z * vs[c * 4 + 2] + xv.w * vs[c * 4 + 3];
        }
        acc += __shfl_xor(acc, 1);
        acc += __shfl_xor(acc, 2);
        if (l4 == 0) s[(size_t)t * N_NODES + row] = acc;
    }
}

__global__ __launch_bounds__(256) void edge_kernel(const int* __restrict__ src,
                                                   const int* __restrict__ dst,
                                                   const float* __restrict__ s,
                                                   unsigned long long* __restrict__ packed) {
    const int t = blockIdx.y;
    const int e4 = blockIdx.x * 256 + threadIdx.x;
    if (e4 * 4 >= N_EDGES) return;
    const int4* sp = (const int4*)(src + (size_t)t * N_EDGES);
    const int4* dp = (const int4*)(dst + (size_t)t * N_EDGES);
    const float* st = s + (size_t)t * N_NODES;
    unsigned long long* pk = packed + (size_t)t * N_NODES;
    const int4 s4 = sp[e4];
    const int4 d4 = dp[e4];
    const float v0 = st[s4.x], v1 = st[s4.y], v2 = st[s4.z], v3 = st[s4.w];
    const unsigned long long base = 1ULL << 41;
    atomicAdd(&pk[d4.x], base + (unsigned long long)(long long)llrintf(v0 * PACK_SCALE));
    atomicAdd(&pk[d4.y], base + (unsigned long long)(long long)llrintf(v1 * PACK_SCALE));
    atomicAdd(&pk[d4.z], base + (unsigned long long)(long long)llrintf(v2 * PACK_SCALE));
    atomicAdd(&pk[d4.w], base + (unsigned long long)(long long)llrintf(v3 * PACK_SCALE));
}

__global__ __launch_bounds__(256) void out_kernel(const unsigned long long* __restrict__ packed,
                                                  const float* __restrict__ bo,
                                                  float* __restrict__ out) {
    const int i = blockIdx.x * 256 + threadIdx.x;
    if (i < T_STEPS * N_NODES) {
        const unsigned long long tot = packed[i];
        const unsigned long long deg = (tot + (1ULL << 40)) >> 41;
        const long long rem = (long long)(tot - (deg << 41));
        const float acc = (float)rem * PACK_INV;
        out[i] = bo[0] + acc / fmaxf((float)deg, 1.0f);
    }
}

extern "C" void kernel_launch(void* const* d_in, const int* in_sizes, int n_in,
                              void* d_out, int out_size, void* d_ws, size_t ws_size,
                              hipStream_t stream) {
    const float* x  = (const float*)d_in[0];
    const int* src  = (const int*)d_in[1];
    const int* dst  = (const int*)d_in[2];
    const float* iw = (const float*)d_in[3];
    const float* Wz = (const float*)d_in[4];
    const float* bz = (const float*)d_in[5];
    const float* Wr = (const float*)d_in[6];
    const float* br = (const float*)d_in[7];
    const float* Wh = (const float*)d_in[8];
    const float* bh = (const float*)d_in[9];
    const float* Wp = (const float*)d_in[10];
    const float* bp = (const float*)d_in[11];
    const float* Wo = (const float*)d_in[12];
    const float* bo = (const float*)d_in[13];
    float* out = (float*)d_out;   // [3*N outs][64*64 w_final]
    float* ws  = (float*)d_ws;

    const size_t FAST_NEED = (size_t)5175456 * sizeof(float);
    if (ws_size >= FAST_NEED) {
        unsigned* recs      = (unsigned*)ws;              // [0,4800000)
        float* colsumP      = ws;                         // [0,150144) dead before K3
        unsigned* histChunk = (unsigned*)(ws + 150144);   // [150144,225216) dead before K3
        unsigned* chunkPref = (unsigned*)(ws + 4800000);  // 75072 u32
        unsigned* bstart    = (unsigned*)(ws + 4875072);  // 192 u32
        float* vbuf         = ws + 4875264;               // 192
        float* sbuf         = ws + 4875456;               // 300000

        prep_kernel<<<dim3(CS_BLOCKS + SC_CHUNKS, 3), 256, 0, stream>>>(x, dst,
                                                                        colsumP, histChunk);
        gru_rows_kernel<<<65, 256, 0, stream>>>(colsumP, iw, Wz, bz, Wr, br, Wh, bh,
                                                Wp, bp, Wo, histChunk, bstart, chunkPref,
                                                vbuf, out + (size_t)T_STEPS * N_NODES);
        scat_smv_kernel<<<dim3(SC_CHUNKS + SMV_BLOCKS, 3), 512, 0, stream>>>(
            x, vbuf, src, dst, bstart, chunkPref, recs, sbuf);
        accum_kernel<<<dim3(NBKT, 3), 512, 0, stream>>>(recs, bstart, sbuf, bo, out);
    } else {
        float* colsumP = ws;                                        // 150144
        float* vbuf    = ws + 150144;                               // 192
        float* sbuf    = ws + 150336;                               // 300000
        unsigned long long* packed = (unsigned long long*)(ws + 450336); // 300000 u64

        hipMemsetAsync(packed, 0, (size_t)600000 * sizeof(float), stream);

        prep_kernel<<<dim3(CS_BLOCKS, 3), 256, 0, stream>>>(x, dst, colsumP,
                                                            (unsigned*)nullptr);
        gru_rows_kernel<<<16, 256, 0, stream>>>(colsumP, iw, Wz, bz, Wr, br, Wh, bh,
                                                Wp, bp, Wo, (unsigned*)nullptr,
                                                (unsigned*)nullptr, (unsigned*)nullptr,
                                                vbuf, out + (size_t)T_STEPS * N_NODES);
        smatvec_kernel<<<dim3(1563, 3), 256, 0, stream>>>(x, vbuf, sbuf);
        edge_kernel<<<dim3(1563, 3), 256, 0, stream>>>(src, dst, sbuf, packed);
        out_kernel<<<1172, 256, 0, stream>>>(packed, bo, out);
    }
}

// Round 13
// 105.397 us; speedup vs baseline: 1.2525x; 1.0450x over previous
//
#include <hip/hip_runtime.h>
#include <math.h>

#define T_STEPS 3
#define N_NODES 100000
#define N_EDGES 1600000
#define N_E4    (N_EDGES / 4)
#define D 64

#define CS_BLOCKS 782       // ceil(100000/128) colsum blocks per t

// Bucket parameters: 512-node buckets (R10-proven)
#define BKT_BITS 9
#define BKT_SIZE 512
#define NBKT 196            // ceil(100000/512)
#define NBKT_PAD 256
#define QSCALE 65536.0f     // 2^16
#define QINV   (1.0f / 65536.0f)

// Chunk parameters: 4096 edges per chunk, chunk == scatter block
#define SC_EPB 4096
#define SC_I4  1024
#define SC_CHUNKS 391       // ceil(1.6M / 4096)

// smatvec-in-K3: 512 threads, 4 lanes/row -> 128 rows/block
#define SMV_BLOCKS 782

// GRU-rows parameters
#define GR_PAD 68

// Fallback parameters
#define PACK_SCALE 1048576.0f
#define PACK_INV   (1.0f / 1048576.0f)

// ---------------------------------------------------------------------------
// FAST ws layout (float offsets) — atomic-free, no memsets (R10 layout):
//   [0,4800000)        recs[3][E] u32   overlaid (dead before K3):
//        [0,150144)        colsumP[3][782][64]
//        [150144,450432)   histChunk[3][391][256] u32
//   [4800000,5100288)  chunkPref[3][391][256] u32
//   [5100288,5101056)  bstart[3][256] u32
//   [5101056,5101248)  v[3][64]
//   [5101248,5401248)  s[3][N]
// rec format: (dst&511)<<17 | src   (src < 2^17)
// recs layout: bucket-contiguous per t (scatter writes runs, accum reads
// coalesced — the sort pays on the write side only).
// ---------------------------------------------------------------------------

// K1: fused prep — blocks [0,782): colsum partials of x_t;
// blocks [782,1173): per-chunk dst bucket histograms.
__global__ __launch_bounds__(256) void prep_kernel(const float* __restrict__ x,
                                                   const int* __restrict__ dst,
                                                   float* __restrict__ colsumP,
                                                   unsigned* __restrict__ histChunk) {
    const int t = blockIdx.y;
    const int tid = threadIdx.x;
    __shared__ float red[16][64];
    __shared__ unsigned h[NBKT_PAD];

    if (blockIdx.x < CS_BLOCKS) {
        const int q = tid & 15;
        const int g = tid >> 4;
        const float4* xt = (const float4*)(x + (size_t)t * N_NODES * D);
        const int base = blockIdx.x * 128;
        float sx = 0.f, sy = 0.f, sz = 0.f, sw = 0.f;
#pragma unroll
        for (int it = 0; it < 8; ++it) {
            const int r = base + g + 16 * it;
            if (r < N_NODES) {
                const float4 vv = xt[(size_t)r * 16 + q];
                sx += vv.x; sy += vv.y; sz += vv.z; sw += vv.w;
            }
        }
        red[g][q * 4 + 0] = sx;
        red[g][q * 4 + 1] = sy;
        red[g][q * 4 + 2] = sz;
        red[g][q * 4 + 3] = sw;
        __syncthreads();
        if (tid < 64) {
            float s = 0.f;
#pragma unroll
            for (int gg = 0; gg < 16; ++gg) s += red[gg][tid];
            colsumP[((size_t)t * CS_BLOCKS + blockIdx.x) * 64 + tid] = s;
        }
    } else {
        const int c = blockIdx.x - CS_BLOCKS;
        h[tid] = 0;
        __syncthreads();
        const int4* dp = (const int4*)(dst + (size_t)t * N_EDGES);
#pragma unroll
        for (int it = 0; it < 4; ++it) {
            const int i4 = c * SC_I4 + it * 256 + tid;
            if (i4 < N_E4) {
                const int4 d = dp[i4];
                atomicAdd(&h[d.x >> BKT_BITS], 1u);
                atomicAdd(&h[d.y >> BKT_BITS], 1u);
                atomicAdd(&h[d.z >> BKT_BITS], 1u);
                atomicAdd(&h[d.w >> BKT_BITS], 1u);
            }
        }
        __syncthreads();
        histChunk[((size_t)t * SC_CHUNKS + c) * NBKT_PAD + tid] = h[tid];
    }
}

__device__ __forceinline__ float fast_sigmoid(float v) {
    return 1.f / (1.f + __expf(-v));
}
__device__ __forceinline__ float fast_tanh(float v) {
    return 1.f - 2.f / (__expf(2.f * v) + 1.f);
}

// K2: blocks 0..15 GRU rows; block 16 bucket-total scan -> bstart;
// blocks 17..208 per-(chunk,bucket) exclusive prefixes -> chunkPref.
__global__ __launch_bounds__(256) void gru_rows_kernel(
    const float* __restrict__ colsumP, const float* __restrict__ iw,
    const float* __restrict__ Wz, const float* __restrict__ bz,
    const float* __restrict__ Wr, const float* __restrict__ br,
    const float* __restrict__ Wh, const float* __restrict__ bh,
    const float* __restrict__ Wp, const float* __restrict__ bp,
    const float* __restrict__ Wo, const unsigned* __restrict__ histChunk,
    unsigned* __restrict__ bstart, unsigned* __restrict__ chunkPref,
    float* __restrict__ v_out, float* __restrict__ w_final) {
    const int tid = threadIdx.x;

    if (blockIdx.x == 16) {
        __shared__ unsigned scn[NBKT_PAD];
        for (int t = 0; t < T_STEPS; ++t) {
            unsigned c = 0;
            for (int k = 0; k < SC_CHUNKS; ++k)
                c += histChunk[((size_t)t * SC_CHUNKS + k) * NBKT_PAD + tid];
            unsigned v = c;
            scn[tid] = v;
            __syncthreads();
            for (int off = 1; off < NBKT_PAD; off <<= 1) {
                const unsigned add = (tid >= off) ? scn[tid - off] : 0u;
                __syncthreads();
                v += add;
                scn[tid] = v;
                __syncthreads();
            }
            bstart[t * NBKT_PAD + tid] = (unsigned)(t * N_EDGES) + (v - c);
            __syncthreads();
        }
        return;
    }
    if (blockIdx.x >= 17) {
        const int idx = blockIdx.x - 17;      // 0..191
        const int t = idx >> 6;
        const int wid = tid >> 6, lane = tid & 63;
        const int b = (idx & 63) * 4 + wid;   // 0..255
        unsigned running = 0;
#pragma unroll
        for (int g = 0; g < 7; ++g) {
            const int c = g * 64 + lane;
            const unsigned val = (c < SC_CHUNKS)
                ? histChunk[((size_t)t * SC_CHUNKS + c) * NBKT_PAD + b] : 0u;
            unsigned incl = val;
#pragma unroll
            for (int off = 1; off < 64; off <<= 1) {
                const unsigned n = __shfl_up(incl, off);
                if (lane >= off) incl += n;
            }
            if (c < SC_CHUNKS)
                chunkPref[((size_t)t * SC_CHUNKS + c) * NBKT_PAD + b] = running + (incl - val);
            running += __shfl(incl, 63);
        }
        return;
    }

    // ---- GRU rows block ----
    __shared__ float BzT[64 * GR_PAD];
    __shared__ float BrT[64 * GR_PAD];
    __shared__ float BhT[64 * GR_PAD];
    __shared__ float w_lds[4 * 64];
    __shared__ float mean_s[192];
    __shared__ float ctx_s[192];
    __shared__ float czrh_s[576];

#pragma unroll
    for (int it = 0; it < 16; ++it) {
        const int idx = it * 256 + tid;
        const int k = idx >> 6, j = idx & 63;
        BzT[j * GR_PAD + k] = Wz[(64 + k) * 64 + j];
        BrT[j * GR_PAD + k] = Wr[(64 + k) * 64 + j];
        BhT[j * GR_PAD + k] = Wh[(64 + k) * 64 + j];
    }
    if (tid < 192) {
        const int t = tid >> 6, j = tid & 63;
        float s = 0.f;
        for (int bx = 0; bx < CS_BLOCKS; ++bx)
            s += colsumP[((size_t)t * CS_BLOCKS + bx) * 64 + j];
        mean_s[tid] = s * (1.f / (float)N_NODES);
    }
    __syncthreads();
    if (tid < 192) {
        const int t = tid >> 6, j = tid & 63;
        float c = bp[j];
        for (int k = 0; k < 64; ++k)
            c = fmaf(mean_s[t * 64 + k], Wp[k * 64 + j], c);
        ctx_s[tid] = c;
    }
    __syncthreads();
    for (int co = (tid >> 6); co < 9; co += 4) {
        const int t = co / 3, m = co - 3 * t, j = tid & 63;
        const float* W = (m == 0) ? Wz : (m == 1) ? Wr : Wh;
        const float* bb = (m == 0) ? bz : (m == 1) ? br : bh;
        float c = bb[j];
        for (int k = 0; k < 64; ++k)
            c = fmaf(ctx_s[t * 64 + k], W[k * 64 + j], c);
        czrh_s[co * 64 + j] = c;
    }
    __syncthreads();

    const int wid = tid >> 6, lane = tid & 63;
    const int row = blockIdx.x * 4 + wid;
    float* wrow = &w_lds[wid * 64];
    float w = iw[row * 64 + lane];
    const float wo = Wo[lane];

    for (int t = 0; t < T_STEPS; ++t) {
        wrow[lane] = w;
        __syncthreads();
        float az = 0.f, ar = 0.f;
#pragma unroll
        for (int k0 = 0; k0 < 64; k0 += 4) {
            const float4 wv = *(const float4*)&wrow[k0];
            const float4 z4 = *(const float4*)&BzT[lane * GR_PAD + k0];
            const float4 r4 = *(const float4*)&BrT[lane * GR_PAD + k0];
            az = fmaf(wv.x, z4.x, az); az = fmaf(wv.y, z4.y, az);
            az = fmaf(wv.z, z4.z, az); az = fmaf(wv.w, z4.w, az);
            ar = fmaf(wv.x, r4.x, ar); ar = fmaf(wv.y, r4.y, ar);
            ar = fmaf(wv.z, r4.z, ar); ar = fmaf(wv.w, r4.w, ar);
        }
        const float z = fast_sigmoid(az + czrh_s[(t * 3 + 0) * 64 + lane]);
        const float r = fast_sigmoid(ar + czrh_s[(t * 3 + 1) * 64 + lane]);
        const float rw = r * w;
        __syncthreads();
        wrow[lane] = rw;
        __syncthreads();
        float ah = 0.f;
#pragma unroll
        for (int k0 = 0; k0 < 64; k0 += 4) {
            const float4 wv = *(const float4*)&wrow[k0];
            const float4 h4 = *(const float4*)&BhT[lane * GR_PAD + k0];
            ah = fmaf(wv.x, h4.x, ah); ah = fmaf(wv.y, h4.y, ah);
            ah = fmaf(wv.z, h4.z, ah); ah = fmaf(wv.w, h4.w, ah);
        }
        const float h = fast_tanh(ah + czrh_s[(t * 3 + 2) * 64 + lane]);
        w = z * w + (1.f - z) * h;
        float vp = w * wo;
        vp += __shfl_xor(vp, 1);
        vp += __shfl_xor(vp, 2);
        vp += __shfl_xor(vp, 4);
        vp += __shfl_xor(vp, 8);
        vp += __shfl_xor(vp, 16);
        vp += __shfl_xor(vp, 32);
        if (lane == 0) v_out[t * 64 + row] = vp;
        __syncthreads();
    }
    w_final[row * 64 + lane] = w;
}

// K3: fused scatter (blocks [0,391)) + smatvec (blocks [391,1173)).
// Scatter: hist -> 2-barrier hybrid wave scan -> rank -> bucket-run writeout.
__global__ __launch_bounds__(512) void scat_smv_kernel(
    const float* __restrict__ x, const float* __restrict__ v,
    const int* __restrict__ src, const int* __restrict__ dst,
    const unsigned* __restrict__ bstart, const unsigned* __restrict__ chunkPref,
    unsigned* __restrict__ recs, float* __restrict__ s) {
    const int t = blockIdx.y;
    const int tid = threadIdx.x;
    __shared__ __align__(16) unsigned char lds_raw[27712];

    if (blockIdx.x >= SC_CHUNKS) {
        // ---- smatvec: 128 rows per block, 4 lanes per row ----
        float* vs = (float*)lds_raw;
        if (tid < 64) vs[tid] = v[t * 64 + tid];
        __syncthreads();
        const int row = (blockIdx.x - SC_CHUNKS) * 128 + (tid >> 2);
        const int l4 = tid & 3;
        if (row < N_NODES) {
            const float4* xr = (const float4*)(x + ((size_t)t * N_NODES + row) * D);
            float acc = 0.f;
#pragma unroll
            for (int i = 0; i < 4; ++i) {
                const int c = i * 4 + l4;
                const float4 xv = xr[c];
                acc += xv.x * vs[c * 4 + 0] + xv.y * vs[c * 4 + 1] +
                       xv.z * vs[c * 4 + 2] + xv.w * vs[c * 4 + 3];
            }
            acc += __shfl_xor(acc, 1);
            acc += __shfl_xor(acc, 2);
            if (l4 == 0) s[(size_t)t * N_NODES + row] = acc;
        }
        return;
    }

    // ---- scatter chunk c ----
    const int c = blockIdx.x;
    unsigned* recL = (unsigned*)lds_raw;                       // 4096 u32
    unsigned short* bktL = (unsigned short*)(lds_raw + 16384); // 4096 u16
    unsigned* bh   = (unsigned*)(lds_raw + 24576);             // 256
    unsigned* lofs = bh + 256;                                 // 256
    unsigned* badj = lofs + 256;                               // 256
    unsigned* wsum = badj + 256;                               // 4

    if (tid < NBKT_PAD) bh[tid] = 0;
    __syncthreads();

    const int4* sp = (const int4*)(src + (size_t)t * N_EDGES);
    const int4* dp = (const int4*)(dst + (size_t)t * N_EDGES);

    unsigned rec[8];
    int bkt[8];
#pragma unroll
    for (int k = 0; k < 8; ++k) bkt[k] = -1;

#pragma unroll
    for (int it = 0; it < 2; ++it) {
        const int i4 = c * SC_I4 + it * 512 + tid;
        if (i4 < N_E4) {
            const int4 sv = sp[i4];
            const int4 dv = dp[i4];
            const int ss[4] = {sv.x, sv.y, sv.z, sv.w};
            const int dd[4] = {dv.x, dv.y, dv.z, dv.w};
#pragma unroll
            for (int j = 0; j < 4; ++j) {
                const int b = dd[j] >> BKT_BITS;
                rec[it * 4 + j] = ((unsigned)(dd[j] & (BKT_SIZE - 1)) << 17) |
                                  (unsigned)ss[j];
                bkt[it * 4 + j] = b;
                atomicAdd(&bh[b], 1u);
            }
        }
    }
    __syncthreads();
    // hybrid exclusive scan over 256 buckets: 4 waves x 64 + wave-sum combine
    unsigned cnt = 0, incl = 0;
    if (tid < NBKT_PAD) {
        cnt = bh[tid];
        incl = cnt;
#pragma unroll
        for (int off = 1; off < 64; off <<= 1) {
            const unsigned n = __shfl_up(incl, off);
            if ((tid & 63) >= off) incl += n;
        }
        if ((tid & 63) == 63) wsum[tid >> 6] = incl;
    }
    __syncthreads();
    if (tid < NBKT_PAD) {
        const int wv = tid >> 6;
        unsigned offs = 0;
#pragma unroll
        for (int k = 0; k < 3; ++k)
            if (k < wv) offs += wsum[k];
        const unsigned ex = offs + incl - cnt;
        lofs[tid] = ex;
        const unsigned base = bstart[t * NBKT_PAD + tid] +
                              chunkPref[((size_t)t * SC_CHUNKS + c) * NBKT_PAD + tid];
        badj[tid] = base - ex;   // mod 2^32 ok
    }
    __syncthreads();
#pragma unroll
    for (int k = 0; k < 8; ++k) {
        if (bkt[k] >= 0) {
            const unsigned pos = atomicAdd(&lofs[bkt[k]], 1u);
            recL[pos] = rec[k];
            bktL[pos] = (unsigned short)bkt[k];
        }
    }
    __syncthreads();
    const int nrec = min(SC_EPB, N_EDGES - c * SC_EPB);
    for (int i = tid; i < nrec; i += 512) {
        const unsigned b = bktL[i];
        recs[badj[b] + (unsigned)i] = recL[i];
    }
}

// K4: per-bucket accumulate — coalesced contiguous record reads,
// gather s[src] (L2), integer u64 LDS bins (deterministic), finalize.
__global__ __launch_bounds__(256) void accum_kernel(const unsigned* __restrict__ recs,
                                                    const unsigned* __restrict__ start,
                                                    const float* __restrict__ s,
                                                    const float* __restrict__ bo,
                                                    float* __restrict__ out) {
    const int b = blockIdx.x;
    const int t = blockIdx.y;
    const int tid = threadIdx.x;
    __shared__ unsigned long long bins[BKT_SIZE];
    bins[tid] = 0ULL;
    bins[tid + 256] = 0ULL;
    __syncthreads();
    const float* st = s + (size_t)t * N_NODES;
    const unsigned s0 = start[t * NBKT_PAD + b];
    const unsigned s1 = start[t * NBKT_PAD + b + 1];
    for (unsigned i = s0 + tid; i < s1; i += 256) {
        const unsigned rec = recs[i];
        const unsigned dl = rec >> 17;
        const long long q = llrintf(st[rec & 0x1FFFFu] * QSCALE);
        atomicAdd(&bins[dl],
                  (unsigned long long)((1ULL << 41) + (unsigned long long)q));
    }
    __syncthreads();
    const float bo0 = bo[0];
#pragma unroll
    for (int k = 0; k < 2; ++k) {
        const int i = tid + k * 256;
        const int node = b * BKT_SIZE + i;
        if (node < N_NODES) {
            const unsigned long long tot = bins[i];
            const unsigned long long deg = (tot + (1ULL << 40)) >> 41;
            const long long rem = (long long)(tot - (deg << 41));
            const float acc = (float)rem * QINV;
            out[(size_t)t * N_NODES + node] = bo0 + acc / fmaxf((float)deg, 1.f);
        }
    }
}

// ---------- fallback path: packed global atomics ----------

__global__ __launch_bounds__(256) void smatvec_kernel(const float* __restrict__ x,
                                                      const float* __restrict__ v,
                                                      float* __restrict__ s) {
    const int t = blockIdx.y;
    const int tid = threadIdx.x;
    const int l4 = tid & 3;
    const int rloc = tid >> 2;
    __shared__ float vs[64];
    if (tid < 64) vs[tid] = v[t * 64 + tid];
    __syncthreads();
    const int row = blockIdx.x * 64 + rloc;
    if (row < N_NODES) {
        const float4* xr = (const float4*)(x + ((size_t)t * N_NODES + row) * D);
        float acc = 0.f;
#pragma unroll
        for (int i = 0; i < 4; ++i) {
            const int c = i * 4 + l4;
            const float4 xv = xr[c];
            acc += xv.x * vs[c * 4 + 0] + xv.y * vs[c * 4 + 1] +
                   xv.z * vs[c * 4 + 2] + xv.w * vs[c * 4 + 3];
        }
        acc += __shfl_xor(acc, 1);
        acc += __shfl_xor(acc, 2);
        if (l4 == 0) s[(size_t)t * N_NODES + row] = acc;
    }
}

__global__ __launch_bounds__(256) void edge_kernel(const int* __restrict__ src,
                                                   const int* __restrict__ dst,
                                                   const float* __restrict__ s,
                                                   unsigned long long* __restrict__ packed) {
    const int t = blockIdx.y;
    const int e4 = blockIdx.x * 256 + threadIdx.x;
    if (e4 * 4 >= N_EDGES) return;
    const int4* sp = (const int4*)(src + (size_t)t * N_EDGES);
    const int4* dp = (const int4*)(dst + (size_t)t * N_EDGES);
    const float* st = s + (size_t)t * N_NODES;
    unsigned long long* pk = packed + (size_t)t * N_NODES;
    const int4 s4 = sp[e4];
    const int4 d4 = dp[e4];
    const float v0 = st[s4.x], v1 = st[s4.y], v2 = st[s4.z], v3 = st[s4.w];
    const unsigned long long base = 1ULL << 41;
    atomicAdd(&pk[d4.x], base + (unsigned long long)(long long)llrintf(v0 * PACK_SCALE));
    atomicAdd(&pk[d4.y], base + (unsigned long long)(long long)llrintf(v1 * PACK_SCALE));
    atomicAdd(&pk[d4.z], base + (unsigned long long)(long long)llrintf(v2 * PACK_SCALE));
    atomicAdd(&pk[d4.w], base + (unsigned long long)(long long)llrintf(v3 * PACK_SCALE));
}

__global__ __launch_bounds__(256) void out_kernel(const unsigned long long* __restrict__ packed,
                                                  const float* __restrict__ bo,
                                                  float* __restrict__ out) {
    const int i = blockIdx.x * 256 + threadIdx.x;
    if (i < T_STEPS * N_NODES) {
        const unsigned long long tot = packed[i];
        const unsigned long long deg = (tot + (1ULL << 40)) >> 41;
        const long long rem = (long long)(tot - (deg << 41));
        const float acc = (float)rem * PACK_INV;
        out[i] = bo[0] + acc / fmaxf((float)deg, 1.0f);
    }
}

extern "C" void kernel_launch(void* const* d_in, const int* in_sizes, int n_in,
                              void* d_out, int out_size, void* d_ws, size_t ws_size,
                              hipStream_t stream) {
    const float* x  = (const float*)d_in[0];
    const int* src  = (const int*)d_in[1];
    const int* dst  = (const int*)d_in[2];
    const float* iw = (const float*)d_in[3];
    const float* Wz = (const float*)d_in[4];
    const float* bz = (const float*)d_in[5];
    const float* Wr = (const float*)d_in[6];
    const float* br = (const float*)d_in[7];
    const float* Wh = (const float*)d_in[8];
    const float* bh = (const float*)d_in[9];
    const float* Wp = (const float*)d_in[10];
    const float* bp = (const float*)d_in[11];
    const float* Wo = (const float*)d_in[12];
    const float* bo = (const float*)d_in[13];
    float* out = (float*)d_out;   // [3*N outs][64*64 w_final]
    float* ws  = (float*)d_ws;

    const size_t FAST_NEED = (size_t)5401248 * sizeof(float);
    if (ws_size >= FAST_NEED) {
        unsigned* recs      = (unsigned*)ws;              // [0,4800000)
        float* colsumP      = ws;                         // [0,150144) dead before K3
        unsigned* histChunk = (unsigned*)(ws + 150144);   // [150144,450432) dead before K3
        unsigned* chunkPref = (unsigned*)(ws + 4800000);  // 300288 u32
        unsigned* bstart    = (unsigned*)(ws + 5100288);  // 768 u32
        float* vbuf         = ws + 5101056;               // 192
        float* sbuf         = ws + 5101248;               // 300000

        prep_kernel<<<dim3(CS_BLOCKS + SC_CHUNKS, 3), 256, 0, stream>>>(x, dst,
                                                                        colsumP, histChunk);
        gru_rows_kernel<<<209, 256, 0, stream>>>(colsumP, iw, Wz, bz, Wr, br, Wh, bh,
                                                 Wp, bp, Wo, histChunk, bstart, chunkPref,
                                                 vbuf, out + (size_t)T_STEPS * N_NODES);
        scat_smv_kernel<<<dim3(SC_CHUNKS + SMV_BLOCKS, 3), 512, 0, stream>>>(
            x, vbuf, src, dst, bstart, chunkPref, recs, sbuf);
        accum_kernel<<<dim3(NBKT, 3), 256, 0, stream>>>(recs, bstart, sbuf, bo, out);
    } else {
        float* colsumP = ws;                                        // 150144
        float* vbuf    = ws + 150144;                               // 192
        float* sbuf    = ws + 150336;                               // 300000
        unsigned long long* packed = (unsigned long long*)(ws + 450336); // 300000 u64

        hipMemsetAsync(packed, 0, (size_t)600000 * sizeof(float), stream);

        prep_kernel<<<dim3(CS_BLOCKS, 3), 256, 0, stream>>>(x, dst, colsumP,
                                                            (unsigned*)nullptr);
        gru_rows_kernel<<<16, 256, 0, stream>>>(colsumP, iw, Wz, bz, Wr, br, Wh, bh,
                                                Wp, bp, Wo, (unsigned*)nullptr,
                                                (unsigned*)nullptr, (unsigned*)nullptr,
                                                vbuf, out + (size_t)T_STEPS * N_NODES);
        smatvec_kernel<<<dim3(1563, 3), 256, 0, stream>>>(x, vbuf, sbuf);
        edge_kernel<<<dim3(1563, 3), 256, 0, stream>>>(src, dst, sbuf, packed);
        out_kernel<<<1172, 256, 0, stream>>>(packed, bo, out);
    }
}